// Round 3
// baseline (116.469 us; speedup 1.0000x reference)
//
#include <hip/hip_runtime.h>
#include <hip/hip_bf16.h>
#include <cstdint>
#include <cstddef>

// Problem constants
#define B_   4
#define C_   256
#define V_   4096            // 64*64 pixels per batch
#define M_   16384           // B_*V_ query rows
#define N_   2048            // past samples
#define K_   256             // embed dim (== bytes per fp8 row)
#define NC_  4
#define TINV 10.0f           // 1/TEMP
#define EPSN 1e-8f

typedef float f32x4 __attribute__((ext_vector_type(4)));

__device__ __forceinline__ void gl2lds16(const void* g, void* l) {
    __builtin_amdgcn_global_load_lds(
        (__attribute__((address_space(1))) void*)g,
        (__attribute__((address_space(3))) void*)l, 16, 0, 0);
}

// ---------------------------------------------------------------------------
// Merged prep kernel. Blocks [0,512): normalize past samples -> fp8 + class.
// Blocks [512,768): normalize+transpose X -> fp8 (M_ x K_) + pixel class.
__global__ __launch_bounds__(256) void prep(
        const float* __restrict__ X, const float* __restrict__ Y,
        const float* __restrict__ P, const float* __restrict__ L,
        unsigned char* __restrict__ Xn, unsigned char* __restrict__ Pn,
        unsigned char* __restrict__ pClass, unsigned char* __restrict__ sClass) {
    __shared__ float tile[256][65];   // [c][v] pad 65: both phases conflict-free
    __shared__ float sq2[16][64];
    __shared__ float inv[64];
    int t = threadIdx.x;

    if (blockIdx.x < 512) {
        // ---- past-sample role: 4 samples per block, one wave each ----
        int w = t >> 6, l = t & 63;
        int n = blockIdx.x * 4 + w;
        const float4* row = (const float4*)(P + (size_t)n * K_);
        float4 v = row[l];
        float s = v.x*v.x + v.y*v.y + v.z*v.z + v.w*v.w;
        #pragma unroll
        for (int m = 1; m < 64; m <<= 1) s += __shfl_xor(s, m);
        float iv = 1.0f / fmaxf(sqrtf(s), EPSN);
        int pk = __builtin_amdgcn_cvt_pk_fp8_f32(v.x * iv, v.y * iv, 0, false);
        pk     = __builtin_amdgcn_cvt_pk_fp8_f32(v.z * iv, v.w * iv, pk, true);
        ((int*)(Pn + (size_t)n * K_))[l] = pk;
        if (l == 0) {
            const float* lr = L + (size_t)n * NC_;
            int best = 0; float bv = lr[0];
            #pragma unroll
            for (int k = 1; k < NC_; k++) { if (lr[k] > bv) { bv = lr[k]; best = k; } }
            sClass[n] = (unsigned char)best;
        }
        return;
    }

    // ---- X role: 64 pixels per block ----
    int bx = blockIdx.x - 512;
    int b  = bx >> 6;
    int v0 = (bx & 63) * 64;
    int vg = t & 15, cs = t >> 4;          // 16 v4-groups x 16 c-slices
    const float* Xb = X + (size_t)b * C_ * V_ + v0;
    f32x4 acc4 = {0.f, 0.f, 0.f, 0.f};
    #pragma unroll
    for (int i = 0; i < 16; i++) {
        int c = i * 16 + cs;
        float4 g = *(const float4*)(Xb + (size_t)c * V_ + 4 * vg);
        tile[c][4*vg+0] = g.x; tile[c][4*vg+1] = g.y;
        tile[c][4*vg+2] = g.z; tile[c][4*vg+3] = g.w;
        acc4[0] += g.x*g.x; acc4[1] += g.y*g.y;
        acc4[2] += g.z*g.z; acc4[3] += g.w*g.w;
    }
    *(f32x4*)(&sq2[cs][4*vg]) = acc4;
    __syncthreads();
    if (t < 64) {
        float s = 0.f;
        #pragma unroll
        for (int c = 0; c < 16; c++) s += sq2[c][t];
        inv[t] = 1.0f / fmaxf(sqrtf(s), EPSN);
        const float* Yb = Y + (size_t)b * NC_ * V_ + v0 + t;
        int best = 0; float bv = Yb[0];
        #pragma unroll
        for (int k = 1; k < NC_; k++) {
            float yv = Yb[(size_t)k * V_];
            if (yv > bv) { bv = yv; best = k; }
        }
        pClass[(size_t)b * V_ + v0 + t] = (unsigned char)best;
    }
    __syncthreads();
    // emission: thread owns a c-pair, packs 2 fp8, 2B store (128B/wave)
    int t2 = t & 127, vh = t >> 7;
    int cp = 2 * t2;
    #pragma unroll
    for (int j = 0; j < 32; j++) {
        int v = vh * 32 + j;
        float iv = inv[v];
        float a = tile[cp][v] * iv, bb2 = tile[cp + 1][v] * iv;
        int pk = __builtin_amdgcn_cvt_pk_fp8_f32(a, bb2, 0, false);
        *(unsigned short*)(Xn + (size_t)(b * V_ + v0 + v) * K_ + cp) =
            (unsigned short)(pk & 0xffff);
    }
}

// ---------------------------------------------------------------------------
// FP8 GEMM (sim = Xn . Pn^T) + exp + class-partitioned per-pixel partials.
// 128x128 tile, BK=64 (bytes), 4 waves 2x2, 16x16x32 fp8 MFMA.
// LDS rows are 64 B; 16B chunks XOR-swizzled: phys = log ^ (row & 3).
// b64 fragment reads land 4 lanes per 8B slot across all 32 banks -> free.
__global__ __launch_bounds__(256) void gemm_loss(
        const unsigned char* __restrict__ A,   // Xn M_ x K_ fp8
        const unsigned char* __restrict__ Bm,  // Pn N_ x K_ fp8
        const unsigned char* __restrict__ pClass,
        const unsigned char* __restrict__ sClass,
        float* __restrict__ pss, float* __restrict__ pso) {
    __shared__ __align__(1024) unsigned char As[128 * 64];
    __shared__ __align__(1024) unsigned char Bs[128 * 64];
    int tid = threadIdx.x;
    int w = tid >> 6, l = tid & 63;
    int m0 = blockIdx.x * 128;
    int n0 = blockIdx.y * 128;
    int wm = (w >> 1) * 64, wn = (w & 1) * 64;
    int q = l >> 4, c0 = l & 15;
    int lrow = l >> 2;                       // staging: 16 rows per 1KB chunk
    int lcsw = 16 * ((l & 3) ^ (lrow & 3));  // swizzled 16B col chunk (bytes)

    f32x4 acc[4][4];
    #pragma unroll
    for (int i = 0; i < 4; i++)
        #pragma unroll
        for (int j = 0; j < 4; j++)
            acc[i][j] = (f32x4){0.f, 0.f, 0.f, 0.f};

    for (int k0 = 0; k0 < K_; k0 += 64) {
        #pragma unroll
        for (int i = 0; i < 2; i++) {
            int c = i * 4 + w;    // chunk 0..7, wave-uniform (16 rows each)
            gl2lds16(A  + (size_t)(m0 + c * 16 + lrow) * K_ + k0 + lcsw, As + c * 1024);
            gl2lds16(Bm + (size_t)(n0 + c * 16 + lrow) * K_ + k0 + lcsw, Bs + c * 1024);
        }
        __syncthreads();
        #pragma unroll
        for (int kk = 0; kk < 64; kk += 32) {
            int phys = ((kk >> 4) + (q >> 1)) ^ (c0 & 3);
            int off  = phys * 16 + (q & 1) * 8;
            long af[4], bfv[4];
            #pragma unroll
            for (int mi = 0; mi < 4; mi++)
                af[mi] = *(const long*)(As + (wm + mi * 16 + c0) * 64 + off);
            #pragma unroll
            for (int ni = 0; ni < 4; ni++)
                bfv[ni] = *(const long*)(Bs + (wn + ni * 16 + c0) * 64 + off);
            #pragma unroll
            for (int mi = 0; mi < 4; mi++)
                #pragma unroll
                for (int ni = 0; ni < 4; ni++)
                    acc[mi][ni] = __builtin_amdgcn_mfma_f32_16x16x32_fp8_fp8(
                        af[mi], bfv[ni], acc[mi][ni], 0, 0, 0);
        }
        __syncthreads();
    }

    // Epilogue: e = exp(10*(sim-1)); partition by class; 16-lane column-group
    // reduce so lane c0==0 writes the per-row partials for this 64-col half.
    int sc[4];
    #pragma unroll
    for (int ni = 0; ni < 4; ni++) sc[ni] = sClass[n0 + wn + ni * 16 + c0];
    int slab = blockIdx.y * 2 + (w & 1);
    #pragma unroll
    for (int mi = 0; mi < 4; mi++) {
        #pragma unroll
        for (int r = 0; r < 4; r++) {
            int row = m0 + wm + mi * 16 + q * 4 + r;
            int pc = pClass[row];
            float ss = 0.f, so = 0.f;
            #pragma unroll
            for (int ni = 0; ni < 4; ni++) {
                float e = __expf((acc[mi][ni][r] - 1.0f) * TINV);
                if (sc[ni] == pc) ss += e; else so += e;
            }
            #pragma unroll
            for (int m = 1; m < 16; m <<= 1) {
                ss += __shfl_xor(ss, m);
                so += __shfl_xor(so, m);
            }
            if (c0 == 0) {
                pss[(size_t)slab * M_ + row] = ss;
                pso[(size_t)slab * M_ + row] = so;
            }
        }
    }
}

// ---------------------------------------------------------------------------
// Per-pixel combine of 32 slabs -> ratio -> per-block sum.
__global__ __launch_bounds__(256) void reduce1(
        const float* __restrict__ pss, const float* __restrict__ pso,
        const unsigned char* __restrict__ pClass,
        const unsigned char* __restrict__ sClass,
        float* __restrict__ bsum) {
    __shared__ int hist[NC_];
    __shared__ float lss[4][64], lso[4][64];
    int t = threadIdx.x;
    if (t < NC_) hist[t] = 0;
    __syncthreads();
    int lc[NC_] = {0, 0, 0, 0};
    #pragma unroll
    for (int i = 0; i < 8; i++) lc[sClass[t * 8 + i]]++;
    #pragma unroll
    for (int k = 0; k < NC_; k++) if (lc[k]) atomicAdd(&hist[k], lc[k]);
    int p = blockIdx.x * 64 + (t & 63);
    int g = t >> 6;
    float ss = 0.f, so = 0.f;
    #pragma unroll
    for (int i = 0; i < 8; i++) {
        int s = g * 8 + i;
        ss += pss[(size_t)s * M_ + p];
        so += pso[(size_t)s * M_ + p];
    }
    lss[g][t & 63] = ss;
    lso[g][t & 63] = so;
    __syncthreads();
    if (t < 64) {
        float S = lss[0][t] + lss[1][t] + lss[2][t] + lss[3][t];
        float O = lso[0][t] + lso[1][t] + lso[2][t] + lso[3][t];
        int cnt = hist[pClass[blockIdx.x * 64 + t]];
        float ratio = (S + (float)(N_ - cnt)) / (O + (float)cnt);
        #pragma unroll
        for (int m = 1; m < 64; m <<= 1) ratio += __shfl_xor(ratio, m);
        if (t == 0) bsum[blockIdx.x] = ratio;
    }
}

// Final 256-value sum -> mean scalar (fully overwrites d_out).
__global__ __launch_bounds__(256) void reduce2(
        const float* __restrict__ bsum, float* __restrict__ out) {
    __shared__ float wsum[4];
    int t = threadIdx.x;
    float v = bsum[t];
    #pragma unroll
    for (int m = 1; m < 64; m <<= 1) v += __shfl_xor(v, m);
    if ((t & 63) == 0) wsum[t >> 6] = v;
    __syncthreads();
    if (t == 0) out[0] = (wsum[0] + wsum[1] + wsum[2] + wsum[3]) * (1.0f / (float)M_);
}

// ---------------------------------------------------------------------------
extern "C" void kernel_launch(void* const* d_in, const int* in_sizes, int n_in,
                              void* d_out, int out_size, void* d_ws, size_t ws_size,
                              hipStream_t stream) {
    const float* X = (const float*)d_in[0];   // (B, C, H, W)
    const float* Y = (const float*)d_in[1];   // (B, NC, H, W)
    const float* P = (const float*)d_in[2];   // (N, C)
    const float* L = (const float*)d_in[3];   // (N, NC)

    char* ws = (char*)d_ws;
    unsigned char* Xn   = (unsigned char*)(ws);              // 4 MB fp8 M_ x K_
    unsigned char* Pn   = (unsigned char*)(ws + 4194304);    // 512 KB fp8 N_ x K_
    float*         pss  = (float*)(ws + 8388608);            // 2 MB [32][M_]
    float*         pso  = (float*)(ws + 10485760);           // 2 MB [32][M_]
    unsigned char* pCls = (unsigned char*)(ws + 12582912);   // 16 KB
    unsigned char* sCls = (unsigned char*)(ws + 12599296);   // 2 KB
    float*         bsum = (float*)(ws + 12601344);           // 1 KB

    prep<<<512 + B_ * (V_ / 64), 256, 0, stream>>>(X, Y, P, L, Xn, Pn, pCls, sCls);
    dim3 grid(M_ / 128, N_ / 128);
    gemm_loss<<<grid, 256, 0, stream>>>(Xn, Pn, pCls, sCls, pss, pso);
    reduce1<<<M_ / 64, 256, 0, stream>>>(pss, pso, pCls, sCls, bsum);
    reduce2<<<1, 256, 0, stream>>>(bsum, (float*)d_out);
}

// Round 4
// 99.871 us; speedup vs baseline: 1.1662x; 1.1662x over previous
//
#include <hip/hip_runtime.h>
#include <hip/hip_bf16.h>
#include <cstdint>
#include <cstddef>

// Problem constants
#define B_   4
#define C_   256
#define V_   4096            // 64*64 pixels per batch
#define M_   16384           // B_*V_ query rows
#define N_   2048            // past samples
#define K_   256             // embed dim (== bytes per fp8 row)
#define NC_  4
#define TINV 10.0f           // 1/TEMP
#define EPSN 1e-8f

typedef float f32x4 __attribute__((ext_vector_type(4)));
typedef int   int4v __attribute__((ext_vector_type(4)));
typedef int   int8v __attribute__((ext_vector_type(8)));

__device__ __forceinline__ void gl2lds16(const void* g, void* l) {
    __builtin_amdgcn_global_load_lds(
        (__attribute__((address_space(1))) void*)g,
        (__attribute__((address_space(3))) void*)l, 16, 0, 0);
}

// ---------------------------------------------------------------------------
// Merged prep. Blocks [0,512): past samples -> fp8 + class.
// Blocks [512,1024): X normalize+transpose -> fp8, 32 pixels/block
// (512 blocks -> ~3 blocks/CU at 40KB LDS; was 1 block/CU before = no hiding).
__global__ __launch_bounds__(256) void prep(
        const float* __restrict__ X, const float* __restrict__ Y,
        const float* __restrict__ P, const float* __restrict__ L,
        unsigned char* __restrict__ Xn, unsigned char* __restrict__ Pn,
        unsigned char* __restrict__ pClass, unsigned char* __restrict__ sClass) {
    __shared__ float tile[256][35];   // [c][v] pad 35 (==3 mod 32): phase1 writes ~2-way
    __shared__ float sq2[32][36];
    __shared__ float inv[32];
    int t = threadIdx.x;

    if (blockIdx.x < 512) {
        // ---- past-sample role: 4 samples per block, one wave each ----
        int w = t >> 6, l = t & 63;
        int n = blockIdx.x * 4 + w;
        const float4* row = (const float4*)(P + (size_t)n * K_);
        float4 v = row[l];
        float s = v.x*v.x + v.y*v.y + v.z*v.z + v.w*v.w;
        #pragma unroll
        for (int m = 1; m < 64; m <<= 1) s += __shfl_xor(s, m);
        float iv = 1.0f / fmaxf(sqrtf(s), EPSN);
        int pk = __builtin_amdgcn_cvt_pk_fp8_f32(v.x * iv, v.y * iv, 0, false);
        pk     = __builtin_amdgcn_cvt_pk_fp8_f32(v.z * iv, v.w * iv, pk, true);
        ((int*)(Pn + (size_t)n * K_))[l] = pk;
        if (l == 0) {
            const float* lr = L + (size_t)n * NC_;
            int best = 0; float bv = lr[0];
            #pragma unroll
            for (int k = 1; k < NC_; k++) { if (lr[k] > bv) { bv = lr[k]; best = k; } }
            sClass[n] = (unsigned char)best;
        }
        return;
    }

    // ---- X role: 32 pixels per block ----
    int bx = blockIdx.x - 512;           // 0..511
    int b  = bx >> 7;                    // 0..3
    int v0 = (bx & 127) * 32;
    int vg = t & 7, cs = t >> 3;         // 8 v4-groups x 32 c-slices
    const float* Xb = X + (size_t)b * C_ * V_ + v0;
    f32x4 acc4 = {0.f, 0.f, 0.f, 0.f};
    #pragma unroll
    for (int i = 0; i < 8; i++) {
        int c = i * 32 + cs;
        float4 g = *(const float4*)(Xb + (size_t)c * V_ + 4 * vg);
        tile[c][4*vg+0] = g.x; tile[c][4*vg+1] = g.y;
        tile[c][4*vg+2] = g.z; tile[c][4*vg+3] = g.w;
        acc4[0] += g.x*g.x; acc4[1] += g.y*g.y;
        acc4[2] += g.z*g.z; acc4[3] += g.w*g.w;
    }
    *(f32x4*)(&sq2[cs][4*vg]) = acc4;
    __syncthreads();
    if (t < 32) {
        float s = 0.f;
        #pragma unroll
        for (int c = 0; c < 32; c++) s += sq2[c][t];
        inv[t] = 1.0f / fmaxf(sqrtf(s), EPSN);
        const float* Yb = Y + (size_t)b * NC_ * V_ + v0 + t;
        int best = 0; float bv = Yb[0];
        #pragma unroll
        for (int k = 1; k < NC_; k++) {
            float yv = Yb[(size_t)k * V_];
            if (yv > bv) { bv = yv; best = k; }
        }
        pClass[(size_t)b * V_ + v0 + t] = (unsigned char)best;
    }
    __syncthreads();
    // emission: thread owns a c-pair; 2B stores are lane-contiguous (coalesced)
    int t2 = t & 127, vh = t >> 7;
    int cp = 2 * t2;
    #pragma unroll
    for (int j = 0; j < 16; j++) {
        int v = vh * 16 + j;
        float iv = inv[v];
        float a = tile[cp][v] * iv, bb2 = tile[cp + 1][v] * iv;
        int pk = __builtin_amdgcn_cvt_pk_fp8_f32(a, bb2, 0, false);
        *(unsigned short*)(Xn + (size_t)(b * V_ + v0 + v) * K_ + cp) =
            (unsigned short)(pk & 0xffff);
    }
}

// ---------------------------------------------------------------------------
// MX-scaled FP8 GEMM (sim = Xn . Pn^T) + exp + class-partitioned partials.
// 128x128 tile, BK=128 bytes, 16x16x128 f8f6f4 MFMA w/ unit scales (0x7F).
// LDS rows 128 B = 8 x 16B chunks, XOR swizzle: phys = log ^ (row & 7).
// Epilogue: per-wave LDS transpose-reduce (reuses tile LDS), 1 float2/lane out.
__global__ __launch_bounds__(256) void gemm_loss(
        const unsigned char* __restrict__ A,   // Xn M_ x K_ fp8
        const unsigned char* __restrict__ Bm,  // Pn N_ x K_ fp8
        const unsigned char* __restrict__ pClass,
        const unsigned char* __restrict__ sClass,
        float2* __restrict__ psso) {
    __shared__ __align__(1024) unsigned char lds[32768];
    unsigned char* As = lds;               // 16 KB: 128 rows x 128 B
    unsigned char* Bs = lds + 16384;       // 16 KB
    int tid = threadIdx.x;
    int w = tid >> 6, l = tid & 63;
    int m0 = blockIdx.x * 128;
    int n0 = blockIdx.y * 128;
    int wm = (w >> 1) * 64, wn = (w & 1) * 64;
    int q = l >> 4, c0 = l & 15;
    int lrow = l >> 3;                     // staging: row within 8-row chunk
    int lcsw = 16 * ((l & 7) ^ lrow);      // swizzled 16B col chunk (bytes)

    f32x4 acc[4][4];
    #pragma unroll
    for (int i = 0; i < 4; i++)
        #pragma unroll
        for (int j = 0; j < 4; j++)
            acc[i][j] = (f32x4){0.f, 0.f, 0.f, 0.f};

    for (int k0 = 0; k0 < 2; k0++) {
        #pragma unroll
        for (int i = 0; i < 4; i++) {
            int c = i * 4 + w;             // chunk 0..15 (8 rows each), wave-uniform
            gl2lds16(A  + (size_t)(m0 + c * 8 + lrow) * K_ + k0 * 128 + lcsw,
                     As + c * 1024);
            gl2lds16(Bm + (size_t)(n0 + c * 8 + lrow) * K_ + k0 * 128 + lcsw,
                     Bs + c * 1024);
        }
        __syncthreads();
        int8v bf[4];
        #pragma unroll
        for (int ni = 0; ni < 4; ni++) {
            int row = wn + ni * 16 + c0;
            int p0 = (2 * q)     ^ (row & 7);
            int p1 = (2 * q + 1) ^ (row & 7);
            int4v lo = *(const int4v*)(Bs + row * 128 + p0 * 16);
            int4v hi = *(const int4v*)(Bs + row * 128 + p1 * 16);
            bf[ni] = __builtin_shufflevector(lo, hi, 0, 1, 2, 3, 4, 5, 6, 7);
        }
        #pragma unroll
        for (int mi = 0; mi < 4; mi++) {
            int row = wm + mi * 16 + c0;
            int p0 = (2 * q)     ^ (row & 7);
            int p1 = (2 * q + 1) ^ (row & 7);
            int4v lo = *(const int4v*)(As + row * 128 + p0 * 16);
            int4v hi = *(const int4v*)(As + row * 128 + p1 * 16);
            int8v af = __builtin_shufflevector(lo, hi, 0, 1, 2, 3, 4, 5, 6, 7);
            #pragma unroll
            for (int ni = 0; ni < 4; ni++)
                acc[mi][ni] = __builtin_amdgcn_mfma_scale_f32_16x16x128_f8f6f4(
                    af, bf[ni], acc[mi][ni], 0, 0,
                    0, 0x7F7F7F7F, 0, 0x7F7F7F7F);   // unit e8m0 scales
        }
        __syncthreads();
    }

    // ---- Epilogue: exp + class partition, LDS transpose-reduce per wave ----
    int sc[4];
    #pragma unroll
    for (int ni = 0; ni < 4; ni++) sc[ni] = sClass[n0 + wn + ni * 16 + c0];
    int slab = blockIdx.y * 2 + (w & 1);
    float2* ep = ((float2*)lds) + w * 1024;     // 8 KB per wave, reuses tiles
    #pragma unroll
    for (int mi = 0; mi < 4; mi++) {
        #pragma unroll
        for (int r = 0; r < 4; r++) {
            int row = m0 + wm + mi * 16 + q * 4 + r;
            int pc = pClass[row];
            float ss = 0.f, so = 0.f;
            #pragma unroll
            for (int ni = 0; ni < 4; ni++) {
                float e = __expf((acc[mi][ni][r] - 1.0f) * TINV);
                if (sc[ni] == pc) ss += e; else so += e;
            }
            int rs = (mi * 4 + r) * 4 + q;             // row-slot 0..63
            ep[rs * 16 + (c0 ^ (rs & 15))] = make_float2(ss, so);
        }
    }
    __syncthreads();
    // lane l reduces row-slot l (16 xor-swizzled ds_read_b64, 4 dwords/bank)
    float ssT = 0.f, soT = 0.f;
    #pragma unroll
    for (int c = 0; c < 16; c++) {
        float2 v = ep[l * 16 + (c ^ (l & 15))];
        ssT += v.x; soT += v.y;
    }
    int mi2 = l >> 4, r2 = l & 3, q2 = (l >> 2) & 3;
    int R = m0 + wm + mi2 * 16 + q2 * 4 + r2;
    psso[(size_t)slab * M_ + R] = make_float2(ssT, soT);
}

// ---------------------------------------------------------------------------
// Per-pixel combine of 32 slabs -> ratio -> per-block sum.
__global__ __launch_bounds__(256) void reduce1(
        const float2* __restrict__ psso,
        const unsigned char* __restrict__ pClass,
        const unsigned char* __restrict__ sClass,
        float* __restrict__ bsum) {
    __shared__ int hist[NC_];
    __shared__ float lss[4][64], lso[4][64];
    int t = threadIdx.x;
    if (t < NC_) hist[t] = 0;
    __syncthreads();
    int lc[NC_] = {0, 0, 0, 0};
    #pragma unroll
    for (int i = 0; i < 8; i++) lc[sClass[t * 8 + i]]++;
    #pragma unroll
    for (int k = 0; k < NC_; k++) if (lc[k]) atomicAdd(&hist[k], lc[k]);
    int p = blockIdx.x * 64 + (t & 63);
    int g = t >> 6;
    float ss = 0.f, so = 0.f;
    #pragma unroll
    for (int i = 0; i < 8; i++) {
        float2 v = psso[(size_t)(g * 8 + i) * M_ + p];
        ss += v.x; so += v.y;
    }
    lss[g][t & 63] = ss;
    lso[g][t & 63] = so;
    __syncthreads();
    if (t < 64) {
        float S = lss[0][t] + lss[1][t] + lss[2][t] + lss[3][t];
        float O = lso[0][t] + lso[1][t] + lso[2][t] + lso[3][t];
        int cnt = hist[pClass[blockIdx.x * 64 + t]];
        float ratio = (S + (float)(N_ - cnt)) / (O + (float)cnt);
        #pragma unroll
        for (int m = 1; m < 64; m <<= 1) ratio += __shfl_xor(ratio, m);
        if (t == 0) bsum[blockIdx.x] = ratio;
    }
}

// Final 256-value sum -> mean scalar (fully overwrites d_out).
__global__ __launch_bounds__(256) void reduce2(
        const float* __restrict__ bsum, float* __restrict__ out) {
    __shared__ float wsum[4];
    int t = threadIdx.x;
    float v = bsum[t];
    #pragma unroll
    for (int m = 1; m < 64; m <<= 1) v += __shfl_xor(v, m);
    if ((t & 63) == 0) wsum[t >> 6] = v;
    __syncthreads();
    if (t == 0) out[0] = (wsum[0] + wsum[1] + wsum[2] + wsum[3]) * (1.0f / (float)M_);
}

// ---------------------------------------------------------------------------
extern "C" void kernel_launch(void* const* d_in, const int* in_sizes, int n_in,
                              void* d_out, int out_size, void* d_ws, size_t ws_size,
                              hipStream_t stream) {
    const float* X = (const float*)d_in[0];   // (B, C, H, W)
    const float* Y = (const float*)d_in[1];   // (B, NC, H, W)
    const float* P = (const float*)d_in[2];   // (N, C)
    const float* L = (const float*)d_in[3];   // (N, NC)

    char* ws = (char*)d_ws;
    unsigned char* Xn   = (unsigned char*)(ws);              // 4 MB fp8 M_ x K_
    unsigned char* Pn   = (unsigned char*)(ws + 4194304);    // 512 KB fp8 N_ x K_
    float2*        psso = (float2*)(ws + 8388608);           // 4 MB [32][M_] float2
    unsigned char* pCls = (unsigned char*)(ws + 12582912);   // 16 KB
    unsigned char* sCls = (unsigned char*)(ws + 12599296);   // 2 KB
    float*         bsum = (float*)(ws + 12601344);           // 1 KB

    prep<<<1024, 256, 0, stream>>>(X, Y, P, L, Xn, Pn, pCls, sCls);
    dim3 grid(M_ / 128, N_ / 128);
    gemm_loss<<<grid, 256, 0, stream>>>(Xn, Pn, pCls, sCls, psso);
    reduce1<<<M_ / 64, 256, 0, stream>>>(psso, pCls, sCls, bsum);
    reduce2<<<1, 256, 0, stream>>>(bsum, (float*)d_out);
}